// Round 3
// baseline (106.749 us; speedup 1.0000x reference)
//
#include <hip/hip_runtime.h>

// NeuralCA: out = clip(x + sum_k sigmoid(10*(conv3x3_k(x) - r_k)) * (p_k - x), 0, 1)
// B=16, H=W=512, NK=16, fp32.
// R3 theory: R1==R2 invariance points at the trans pipe (32 trans/px, identical in
// both) running ~1/16 rate -> ~27us of the ~40us kernel. This round: exp-only
// sigmoid (1 trans instead of exp+rcp) via reflection + deg-5 poly of 1/(1+e) on
// e in [0,1]. Structure otherwise identical to R2 to isolate the variable.

#define NK 16
#define BATCH 16
#define H 512
#define W 512
#define G2 14.4269504088896340f   // GAIN(=10) * log2(e)

#if __has_builtin(__builtin_amdgcn_exp2f)
#define EXP2F(x) __builtin_amdgcn_exp2f(x)
#else
#define EXP2F(x) exp2f(x)
#endif

// q(e) = 1/(1+e) - 0.5 on [0,1]; deg-5 Chebyshev truncation, |err| < 5e-5.
#define P0 0.49995667f
#define P1 -0.99662610f
#define P2 0.95608720f
#define P3 -0.77780000f
#define P4 0.42600960f
#define P5 -0.10765824f

// Constant address space -> guaranteed s_load (SGPR broadcast)
typedef const __attribute__((address_space(4))) float cfloat;

__global__ __launch_bounds__(256) void nca_kernel(
    const float* __restrict__ x,
    const float* __restrict__ kernels,
    const float* __restrict__ reactants,
    const float* __restrict__ products,
    float* __restrict__ out)
{
    // One thread per 2x4 pixel tile. Tiles: 16 * 256 * 128 = 2^19 threads.
    const int idx = blockIdx.x * blockDim.x + threadIdx.x;
    const int w4 = (idx & 127) << 2;        // tile start col (128 tiles/row)
    const int h0 = ((idx >> 7) & 255) << 1; // tile start row
    const int b  = idx >> 15;

    const float* xb = x + (size_t)b * (H * W);

    // 4 rows x 6 cols register window (rows h0-1 .. h0+2, halo 1 each side in w)
    float v[4][6];
#pragma unroll
    for (int r = 0; r < 4; ++r) {
        const int row = h0 + r - 1;
        if (row >= 0 && row < H) {
            const float* xr = xb + row * W;
            const float4 c = *(const float4*)(xr + w4);
            v[r][1] = c.x; v[r][2] = c.y; v[r][3] = c.z; v[r][4] = c.w;
            v[r][0] = (w4 > 0)     ? xr[w4 - 1] : 0.0f;   // zero pad left
            v[r][5] = (w4 + 4 < W) ? xr[w4 + 4] : 0.0f;   // zero pad right
        } else {
#pragma unroll
            for (int c = 0; c < 6; ++c) v[r][c] = 0.0f;   // zero pad top/bottom
        }
    }

    cfloat* kc = (cfloat*)kernels;
    cfloat* rc = (cfloat*)reactants;
    cfloat* pc = (cfloat*)products;

    // sum_k p_k (scalar, amortized over 128 px-k evals)
    float sumP = 0.0f;
#pragma unroll
    for (int k = 0; k < NK; ++k) sumP += pc[k];

    // sig_k = 0.5 + sq_k where sq_k = copysign(1/(1+2^-|t|) - 0.5, t), t = G2*(N-r_k)
    // sum_k sig_k        = 8 + sum_k sq_k
    // sum_k sig_k * p_k  = 0.5*sumP + sum_k sq_k * p_k
    float s0[2][4] = {{0.f,0.f,0.f,0.f},{0.f,0.f,0.f,0.f}};  // sum sq
    float s1[2][4] = {{0.f,0.f,0.f,0.f},{0.f,0.f,0.f,0.f}};  // sum sq*p_k

#pragma unroll
    for (int k = 0; k < NK; ++k) {
        float wk[9];
#pragma unroll
        for (int i = 0; i < 9; ++i) wk[i] = kc[k * 9 + i];
        const float c2 = -G2 * rc[k];   // t = fma(G2, N, c2)
        const float pk = pc[k];

#pragma unroll
        for (int py = 0; py < 2; ++py) {
#pragma unroll
            for (int p = 0; p < 4; ++p) {
                float n = 0.0f;
#pragma unroll
                for (int r = 0; r < 3; ++r)
#pragma unroll
                    for (int c = 0; c < 3; ++c)
                        n = fmaf(v[py + r][p + c], wk[r * 3 + c], n);
                const float t = fmaf(G2, n, c2);
                const float e = EXP2F(-__builtin_fabsf(t));   // 1 trans, mods fold
                float q = fmaf(P5, e, P4);
                q = fmaf(q, e, P3);
                q = fmaf(q, e, P2);
                q = fmaf(q, e, P1);
                q = fmaf(q, e, P0);                           // q = 1/(1+e) - 0.5
                const float sq = copysignf(q, t);             // v_bfi
                s0[py][p] += sq;
                s1[py][p] = fmaf(sq, pk, s1[py][p]);
            }
        }
    }

#pragma unroll
    for (int py = 0; py < 2; ++py) {
        float4 o;
        float* op = &o.x;
#pragma unroll
        for (int p = 0; p < 4; ++p) {
            const float xv = v[py + 1][p + 1];
            const float sigsum = 8.0f + s0[py][p];
            const float sigp   = fmaf(0.5f, sumP, s1[py][p]);
            float res = xv + sigp - xv * sigsum;
            op[p] = fminf(fmaxf(res, 0.0f), 1.0f);
        }
        *(float4*)(out + ((size_t)(b * H + h0 + py) * W + w4)) = o;
    }
}

extern "C" void kernel_launch(void* const* d_in, const int* in_sizes, int n_in,
                              void* d_out, int out_size, void* d_ws, size_t ws_size,
                              hipStream_t stream) {
    const float* x         = (const float*)d_in[0];
    const float* kernels   = (const float*)d_in[1];
    const float* reactants = (const float*)d_in[2];
    const float* products  = (const float*)d_in[3];
    float* out = (float*)d_out;

    const int total_tiles = BATCH * (H / 2) * (W / 4);  // 2^19
    nca_kernel<<<total_tiles / 256, 256, 0, stream>>>(x, kernels, reactants, products, out);
}

// Round 4
// 90.995 us; speedup vs baseline: 1.1731x; 1.1731x over previous
//
#include <hip/hip_runtime.h>

// NeuralCA: out = clip(x + sum_k sigmoid(10*(conv3x3_k(x) - r_k)) * (p_k - x), 0, 1)
// B=16, H=W=512, NK=16, fp32.
// R4 theory: R1-R3 times track total VALU instr count (VALU-issue-bound, ~3cyc/instr,
// 8% HBM). R3's VGPR_Count=28 < 36 live values needed => allocator starved the window,
// forcing per-(px,k) L1 reloads (the 1.8x inflation + 27% stall).
// Fix: (a) __launch_bounds__(256,4) -> 128-VGPR budget, window stays resident;
//      (b) packed fp32: float2 pixel pairs -> v_pk_fma_f32 for conv/z/add/accum
//          (13 pk + 4 trans per 2 pixels vs ~30 scalar instrs).

#define NK 16
#define BATCH 16
#define H 512
#define W 512
#define G2 14.4269504088896340f   // GAIN(=10) * log2(e)

typedef float f2 __attribute__((ext_vector_type(2)));

#if __has_builtin(__builtin_amdgcn_exp2f)
#define EXP2F(x) __builtin_amdgcn_exp2f(x)
#else
#define EXP2F(x) exp2f(x)
#endif

#if __has_builtin(__builtin_elementwise_fma)
#define FMA2(a, b, c) __builtin_elementwise_fma((a), (b), (c))
#else
#define FMA2(a, b, c) ((a) * (b) + (c))   // fp-contract=fast folds to fma.v2f32
#endif

static __device__ __forceinline__ f2 bc2(float s) { f2 r; r.x = s; r.y = s; return r; }

// Constant address space -> guaranteed s_load (SGPR broadcast)
typedef const __attribute__((address_space(4))) float cfloat;

__global__ __launch_bounds__(256, 4) void nca_kernel(
    const float* __restrict__ x,
    const float* __restrict__ kernels,
    const float* __restrict__ reactants,
    const float* __restrict__ products,
    float* __restrict__ out)
{
    // One thread per 2x4 pixel tile. Tiles: 16 * 256 * 128 = 2^19 threads.
    const int idx = blockIdx.x * blockDim.x + threadIdx.x;
    const int w4 = (idx & 127) << 2;        // tile start col (128 tiles/row)
    const int h0 = ((idx >> 7) & 255) << 1; // tile start row
    const int b  = idx >> 15;

    const float* xb = x + (size_t)b * (H * W);

    // 4 rows x 6 cols register window (rows h0-1 .. h0+2, halo 1 each side in w)
    float v[4][6];
#pragma unroll
    for (int r = 0; r < 4; ++r) {
        const int row = h0 + r - 1;
        if (row >= 0 && row < H) {
            const float* xr = xb + row * W;
            const float4 c = *(const float4*)(xr + w4);
            v[r][1] = c.x; v[r][2] = c.y; v[r][3] = c.z; v[r][4] = c.w;
            v[r][0] = (w4 > 0)     ? xr[w4 - 1] : 0.0f;   // zero pad left
            v[r][5] = (w4 + 4 < W) ? xr[w4 + 4] : 0.0f;   // zero pad right
        } else {
#pragma unroll
            for (int c = 0; c < 6; ++c) v[r][c] = 0.0f;   // zero pad top/bottom
        }
    }

    // Shifted float2 slices: sl[r][s] = {v[r][s], v[r][s+1]}, s = 0..4.
    // Built once, reused by all 16 kernels. Output pair g (local cols 2g,2g+1)
    // tap c uses sl[r][2g+c]; its center x pair is sl[py+1][2g+1].
    f2 sl[4][5];
#pragma unroll
    for (int r = 0; r < 4; ++r)
#pragma unroll
        for (int s = 0; s < 5; ++s) { sl[r][s].x = v[r][s]; sl[r][s].y = v[r][s + 1]; }

    cfloat* kc = (cfloat*)kernels;
    cfloat* rc = (cfloat*)reactants;
    cfloat* pc = (cfloat*)products;

    // delta = (sum_k sig_k*p_k) - x*(sum_k sig_k), accumulated as float2 pairs
    f2 s0[2][2], s1[2][2];
#pragma unroll
    for (int py = 0; py < 2; ++py)
#pragma unroll
        for (int g = 0; g < 2; ++g) { s0[py][g] = bc2(0.0f); s1[py][g] = bc2(0.0f); }

    const f2 mg2 = bc2(-G2);
    const f2 one = bc2(1.0f);

#pragma unroll
    for (int k = 0; k < NK; ++k) {
        f2 wk[9];
#pragma unroll
        for (int i = 0; i < 9; ++i) wk[i] = bc2(kc[k * 9 + i]);
        const f2 c2 = bc2(G2 * rc[k]);    // z = c2 - G2*N ; 2^z = exp(-10*(N-r_k))
        const f2 pk = bc2(pc[k]);

#pragma unroll
        for (int py = 0; py < 2; ++py) {
#pragma unroll
            for (int g = 0; g < 2; ++g) {
                f2 n = bc2(0.0f);
#pragma unroll
                for (int r = 0; r < 3; ++r)
#pragma unroll
                    for (int c = 0; c < 3; ++c)
                        n = FMA2(sl[py + r][2 * g + c], wk[r * 3 + c], n);
                const f2 z = FMA2(mg2, n, c2);          // pk fma
                f2 e;
                e.x = EXP2F(z.x);                        // v_exp_f32 x2
                e.y = EXP2F(z.y);
                const f2 d = e + one;                    // pk add
                f2 sig;
                sig.x = __builtin_amdgcn_rcpf(d.x);      // v_rcp_f32 x2
                sig.y = __builtin_amdgcn_rcpf(d.y);
                s0[py][g] = s0[py][g] + sig;             // pk add
                s1[py][g] = FMA2(sig, pk, s1[py][g]);    // pk fma
            }
        }
    }

#pragma unroll
    for (int py = 0; py < 2; ++py) {
        float4 o;
#pragma unroll
        for (int g = 0; g < 2; ++g) {
            const f2 xv = sl[py + 1][2 * g + 1];         // center pixels of pair
            f2 res = FMA2(-xv, s0[py][g], xv + s1[py][g]);
            res.x = fminf(fmaxf(res.x, 0.0f), 1.0f);
            res.y = fminf(fmaxf(res.y, 0.0f), 1.0f);
            if (g == 0) { o.x = res.x; o.y = res.y; }
            else        { o.z = res.x; o.w = res.y; }
        }
        *(float4*)(out + ((size_t)(b * H + h0 + py) * W + w4)) = o;
    }
}

extern "C" void kernel_launch(void* const* d_in, const int* in_sizes, int n_in,
                              void* d_out, int out_size, void* d_ws, size_t ws_size,
                              hipStream_t stream) {
    const float* x         = (const float*)d_in[0];
    const float* kernels   = (const float*)d_in[1];
    const float* reactants = (const float*)d_in[2];
    const float* products  = (const float*)d_in[3];
    float* out = (float*)d_out;

    const int total_tiles = BATCH * (H / 2) * (W / 4);  // 2^19
    nca_kernel<<<total_tiles / 256, 256, 0, stream>>>(x, kernels, reactants, products, out);
}